// Round 8
// baseline (241.801 us; speedup 1.0000x reference)
//
#include <hip/hip_runtime.h>
#include <hip/hip_bf16.h>
#include <math.h>

namespace {
constexpr int B_ = 4, HQ_ = 32, HK_ = 8, G_ = 4, M_ = 16;
constexpr int N_ = 8192, D_ = 128, S_ = 256, O_ = 8;
constexpr int TN = 64;               // n-rows per block
constexpr float TAU  = 1e-3f;        // inlier sign: |dot| below -> exact fp64 recheck
constexpr float TAUO = 1e-4f;        // outlier sign: |dot| below -> exact fp64 recheck
}

typedef short short8 __attribute__((ext_vector_type(8)));
typedef float f32x4 __attribute__((ext_vector_type(4)));
typedef unsigned int uint4_ __attribute__((ext_vector_type(4)));
typedef unsigned long long ull2 __attribute__((ext_vector_type(2)));

__device__ inline unsigned short f2bf_rne(float f) {
    unsigned u = __float_as_uint(f);
    u += 0x7FFF + ((u >> 16) & 1);
    return (unsigned short)(u >> 16);
}
__device__ inline float bf2f(unsigned short h) {
    return __uint_as_float(((unsigned)h) << 16);
}

// ---------------- kernel P-split: PtHi/PtLo[s][d] = bf16 hi/lo of P[d][s]; Pt32 fp32 ----
__global__ __launch_bounds__(256) void qjl_prept(const float* __restrict__ P,
                                                 unsigned short* __restrict__ PtHi,
                                                 unsigned short* __restrict__ PtLo,
                                                 float* __restrict__ Pt32) {
    const int d = blockIdx.x;      // 0..127
    const int s = threadIdx.x;     // 0..255
    const float f = P[d * S_ + s];
    const unsigned short hb = f2bf_rne(f);
    const float lof = f - bf2f(hb);
    PtHi[s * D_ + d] = hb;
    PtLo[s * D_ + d] = f2bf_rne(lof);
    Pt32[s * D_ + d] = f;
}

// ---------------- kernel A: sqHi[head][m][s] = bf16(q · P); qT[head][d][m] = q^T ----
__global__ __launch_bounds__(256) void qjl_sketch_q(const float* __restrict__ q,
                                                    const float* __restrict__ P,
                                                    unsigned short* __restrict__ sqHi,
                                                    float* __restrict__ qT) {
    __shared__ float qs[M_][D_];
    const int tid = threadIdx.x;
    const size_t blk = blockIdx.x;  // b*HQ + hq
    const float* qb = q + blk * (size_t)(M_ * D_);
    for (int i = tid; i < M_ * D_ / 4; i += 256)
        reinterpret_cast<float4*>(&qs[0][0])[i] = reinterpret_cast<const float4*>(qb)[i];
    __syncthreads();
    float* qtb = qT + blk * (size_t)(D_ * M_);
    for (int i = tid; i < D_ * M_ / 4; i += 256) {
        const int d = i >> 2;
        const int m4 = i & 3;
        float4 v;
        v.x = qs[m4 * 4 + 0][d];
        v.y = qs[m4 * 4 + 1][d];
        v.z = qs[m4 * 4 + 2][d];
        v.w = qs[m4 * 4 + 3][d];
        reinterpret_cast<float4*>(qtb)[i] = v;
    }
    float acc[M_];
#pragma unroll
    for (int m = 0; m < M_; ++m) acc[m] = 0.f;
    const int s = tid;
    for (int d = 0; d < D_; ++d) {
        const float pv = P[d * S_ + s];
#pragma unroll
        for (int m = 0; m < M_; ++m) acc[m] = fmaf(qs[m][d], pv, acc[m]);
    }
    unsigned short* ob = sqHi + blk * (size_t)(M_ * S_);
#pragma unroll
    for (int m = 0; m < M_; ++m) ob[m * S_ + s] = f2bf_rne(acc[m]);
}

// rare cooperative path: exact fp64 sign of k_in[row] . P[:,col]; all 64 lanes of the
// calling wave participate.
__device__ __noinline__ float qjl_fix_coop(const float* __restrict__ drow,
                                           const float* __restrict__ Pt32,
                                           int col, unsigned long long ip,
                                           float a, int src) {
    const int lane = threadIdx.x & 63;
    const float2 dv = *reinterpret_cast<const float2*>(&drow[2 * lane]);
    const float2 pv = *reinterpret_cast<const float2*>(&Pt32[(size_t)col * D_ + 2 * lane]);
    double p = 0.0;
#pragma unroll
    for (int e = 0; e < 2; ++e) {
        const int d = 2 * lane + e;
        const float v = e ? dv.y : dv.x;
        const float pw = e ? pv.y : pv.x;
        bool isout = false;
#pragma unroll
        for (int j = 0; j < 8; ++j)
            isout = isout || (((unsigned)(ip >> (8 * j)) & 0xFFu) == (unsigned)d);
        if (!isout) p = fma((double)v, (double)pw, p);
    }
#pragma unroll
    for (int off = 1; off < 64; off <<= 1) p += __shfl_xor(p, off);
    if (lane == src) a = (p > 0.0) ? 1.f : -1.f;
    return a;
}

// ---------------- kernel 1: signs + norms + outlier state (512 threads / 8 waves) ----
// grid (N/TN, HK, B). Phase C: wave wv owns all 64 rows x cols [32wv, 32wv+32)
// (2 t-tiles). Writes per-row state to ws for kernel 2.
__global__ __launch_bounds__(512) void qjl_signs(const float* __restrict__ data,
                                                 const float* __restrict__ P,
                                                 const int* __restrict__ oidx,
                                                 const unsigned short* __restrict__ PtHi,
                                                 const unsigned short* __restrict__ PtLo,
                                                 const float* __restrict__ Pt32,
                                                 unsigned long long* __restrict__ wordsg,
                                                 float* __restrict__ sning,
                                                 float* __restrict__ su2g,
                                                 unsigned long long* __restrict__ sidxpg) {
    __shared__ unsigned short abuf[16384];        // 32 KB: hi [0..8191], lo [8192..], XOR-swz
    __shared__ unsigned long long sidxp[TN];
    __shared__ float sfull[TN];
    __shared__ float snout[TN];

    const int tid = threadIdx.x;
    const int lane = tid & 63;
    const int wv = tid >> 6;                      // 0..7
    const int l15 = lane & 15;
    const int kgrp = (lane >> 4) << 3;
    const int nt = blockIdx.x, hk = blockIdx.y, b = blockIdx.z;
    const int n0 = nt * TN;
    const size_t rowbase = (size_t)(b * HK_ + hk) * N_ + n0;
    const size_t wblk = (size_t)((b * HK_ + hk) * (N_ / TN) + nt);
    const float* dbase = data + ((size_t)(b * HK_ + hk) * N_) * D_;

    // ---- phase 0: load data tile, bf16 hi/lo split into LDS, per-row sumsq ----
    {
        const int r = tid >> 3;                   // row 0..63 (8 threads/row)
        const int c = tid & 7;
        const float* drow = dbase + (size_t)(n0 + r) * D_;
        const int swz = (r & 7) << 3;
        float ssq = 0.f;
#pragma unroll
        for (int k = 0; k < 4; ++k) {
            const int f = c + 8 * k;
            float4 v = reinterpret_cast<const float4*>(drow)[f];
            ssq += v.x * v.x + v.y * v.y + v.z * v.z + v.w * v.w;
            unsigned short h0 = f2bf_rne(v.x), h1 = f2bf_rne(v.y),
                           h2 = f2bf_rne(v.z), h3 = f2bf_rne(v.w);
            unsigned short l0 = f2bf_rne(v.x - bf2f(h0)), l1 = f2bf_rne(v.y - bf2f(h1)),
                           l2 = f2bf_rne(v.z - bf2f(h2)), l3 = f2bf_rne(v.w - bf2f(h3));
            const int ei = r * 128 + ((4 * f) ^ swz);
            unsigned long long hw = (unsigned long long)h0 | ((unsigned long long)h1 << 16) |
                                    ((unsigned long long)h2 << 32) | ((unsigned long long)h3 << 48);
            unsigned long long lw = (unsigned long long)l0 | ((unsigned long long)l1 << 16) |
                                    ((unsigned long long)l2 << 32) | ((unsigned long long)l3 << 48);
            *reinterpret_cast<unsigned long long*>(&abuf[ei]) = hw;
            *reinterpret_cast<unsigned long long*>(&abuf[8192 + ei]) = lw;
        }
        ssq += __shfl_xor(ssq, 1);
        ssq += __shfl_xor(ssq, 2);
        ssq += __shfl_xor(ssq, 4);
        if (c == 0) sfull[r] = ssq;
    }
    __syncthreads();

    // ---- phase A: dedup outliers, zero them in LDS, norms; write snin/sidxp out ----
    if (tid < TN) {
        const int n = tid;
        const int* ob = oidx + ((size_t)(b * HK_ + hk) * N_ + n0 + n) * O_;
        const float* drow = dbase + (size_t)(n0 + n) * D_;
        int id[O_];
        int4 i0 = reinterpret_cast<const int4*>(ob)[0];
        int4 i1 = reinterpret_cast<const int4*>(ob)[1];
        id[0] = i0.x; id[1] = i0.y; id[2] = i0.z; id[3] = i0.w;
        id[4] = i1.x; id[5] = i1.y; id[6] = i1.z; id[7] = i1.w;
        const int swz = (n & 7) << 3;
        unsigned long long ip = 0;
        float so2 = 0.f;
#pragma unroll
        for (int j = 0; j < O_; ++j) {
            bool dup = false;
#pragma unroll
            for (int jj = 0; jj < O_; ++jj)
                if (jj < j) dup = dup || (id[jj] == id[j]);
            if (!dup) {
                const float v = drow[id[j]];
                so2 = fmaf(v, v, so2);
                ip |= (unsigned long long)(id[j] & 0xFF) << (8 * j);
                const int ei = n * 128 + (id[j] ^ swz);
                abuf[ei] = 0;
                abuf[8192 + ei] = 0;
            } else {
                ip |= 0xFFull << (8 * j);
            }
        }
        sidxp[n] = ip;
        sidxpg[rowbase + n] = ip;
        const float CIN = (float)(1.2533141373155003 / 256.0);
        const float COUT = (float)(1.2533141373155003 / 64.0);
        sning[rowbase + n] = CIN * sqrtf(fmaxf(sfull[n] - so2, 0.f));
        snout[n] = COUT * sqrtf(so2);
    }
    __syncthreads();

    // ---- phase B: sign_out fp32 + rare exact fp64; write su2 out (8 threads/row) ----
    {
        const int n = tid >> 3;
        const int c = tid & 7;
        const unsigned long long ip = sidxp[n];
        const float* drow = dbase + (size_t)(n0 + n) * D_;
        float u[O_], vv[O_];
        const float* pr[O_];
        bool val[O_];
#pragma unroll
        for (int j = 0; j < O_; ++j) {
            u[j] = 0.f;
            const unsigned bt = (unsigned)(ip >> (8 * j)) & 0xFFu;
            val[j] = (bt != 0xFFu);
            const int ix = (int)(bt & 0x7Fu);
            pr[j] = P + ix * S_;
            vv[j] = val[j] ? drow[ix] : 0.f;
        }
#pragma unroll
        for (int ch = 0; ch < 2; ++ch) {
            const int tc = c * 8 + ch * 4;
            float4 pj[O_];
#pragma unroll
            for (int j = 0; j < O_; ++j)
                pj[j] = *reinterpret_cast<const float4*>(pr[j] + tc);
#pragma unroll
            for (int e = 0; e < 4; ++e) {
                float cs = 0.f;
#pragma unroll
                for (int j = 0; j < O_; ++j)
                    cs = fmaf(vv[j], pj[j][e], cs);
                float sg;
                if (fabsf(cs) < TAUO) {   // rare exact path
                    double cd = 0.0;
#pragma unroll
                    for (int j = 0; j < O_; ++j)
                        cd = fma((double)vv[j], (double)pj[j][e], cd);
                    sg = (cd > 0.0) ? 1.f : ((cd < 0.0) ? -1.f : 0.f);
                } else {
                    sg = (cs > 0.f) ? 1.f : -1.f;
                }
#pragma unroll
                for (int j = 0; j < O_; ++j)
                    u[j] = fmaf(sg, pj[j][e], u[j]);
            }
        }
#pragma unroll
        for (int j = 0; j < O_; ++j) {
            u[j] += __shfl_xor(u[j], 1);
            u[j] += __shfl_xor(u[j], 2);
            u[j] += __shfl_xor(u[j], 4);
        }
        if (c == 0) {
            const float cno = snout[n];
            float o[O_];
#pragma unroll
            for (int j = 0; j < O_; ++j) o[j] = val[j] ? u[j] * cno : 0.f;
            float* sp = su2g + (rowbase + n) * O_;
            *reinterpret_cast<f32x4*>(sp) = (f32x4){o[0], o[1], o[2], o[3]};
            *reinterpret_cast<f32x4*>(sp + 4) = (f32x4){o[4], o[5], o[6], o[7]};
        }
    }
    // no barrier: phase C reads abuf (stable since phase A's barrier)

    // ---- phase C: signs via bf16 hi/lo MFMA; wave owns 2 t-tiles (32 cols) ----
    {
        const int t0 = wv * 2;
#pragma unroll
        for (int ti = 0; ti < 2; ++ti) {
            const int t = t0 + ti;
            short8 bhi[4], blo[4];
            const size_t bo = (size_t)(16 * t + l15) * D_ + kgrp;
#pragma unroll
            for (int ks = 0; ks < 4; ++ks) {
                bhi[ks] = *reinterpret_cast<const short8*>(PtHi + bo + ks * 32);
                blo[ks] = *reinterpret_cast<const short8*>(PtLo + bo + ks * 32);
            }
#pragma unroll
            for (int rt = 0; rt < 4; ++rt) {
                const int arow = 16 * rt + l15;
                const int aswz = (arow & 7) << 3;
                short8 ahi[4], alo[4];
#pragma unroll
                for (int ks = 0; ks < 4; ++ks) {
                    const int ei = arow * 128 + ((ks * 32 + kgrp) ^ aswz);
                    ahi[ks] = *reinterpret_cast<const short8*>(&abuf[ei]);
                    alo[ks] = *reinterpret_cast<const short8*>(&abuf[8192 + ei]);
                }
                f32x4 ac1 = (f32x4){0.f, 0.f, 0.f, 0.f};
                f32x4 ac2 = (f32x4){0.f, 0.f, 0.f, 0.f};
                f32x4 ac3 = (f32x4){0.f, 0.f, 0.f, 0.f};
#pragma unroll
                for (int ks = 0; ks < 4; ++ks) {
                    ac1 = __builtin_amdgcn_mfma_f32_16x16x32_bf16(ahi[ks], bhi[ks], ac1, 0, 0, 0);
                    ac2 = __builtin_amdgcn_mfma_f32_16x16x32_bf16(ahi[ks], blo[ks], ac2, 0, 0, 0);
                    ac3 = __builtin_amdgcn_mfma_f32_16x16x32_bf16(alo[ks], bhi[ks], ac3, 0, 0, 0);
                }
                f32x4 a = (ac1 + ac2) + ac3;
                const float mn = fminf(fminf(fabsf(a[0]), fabsf(a[1])),
                                       fminf(fabsf(a[2]), fabsf(a[3])));
                if (__ballot(mn < TAU) != 0ull) {   // rare
#pragma unroll
                    for (int r = 0; r < 4; ++r) {
                        unsigned long long low = __ballot(fabsf(a[r]) < TAU);
                        while (low) {
                            const int src = __ffsll((unsigned long long)low) - 1;
                            low &= low - 1;
                            const int row = 16 * rt + ((src >> 4) << 2) + r;
                            const int col = 16 * t + (src & 15);
                            a[r] = qjl_fix_coop(dbase + (size_t)(n0 + row) * D_, Pt32, col,
                                                sidxp[row], a[r], src);
                        }
                    }
                }
                unsigned long long bb0 = __ballot(a[0] > 0.f);
                unsigned long long bb1 = __ballot(a[1] > 0.f);
                unsigned long long bb2 = __ballot(a[2] > 0.f);
                unsigned long long bb3 = __ballot(a[3] > 0.f);
                if (lane == 0) {
                    unsigned long long* wp = wordsg + (wblk * 256 + (size_t)(rt * 16 + t) * 4);
                    *reinterpret_cast<ull2*>(wp) = (ull2){bb0, bb1};
                    *reinterpret_cast<ull2*>(wp + 2) = (ull2){bb2, bb3};
                }
            }
        }
    }
}

// ---------------- kernel 2: expand signs + output GEMM (512 threads / 8 waves) ----
// Two waves per head: wave wv handles head hk*G + (wv&3), ct in {(wv>>2)*2, +1}.
__global__ __launch_bounds__(512) void qjl_out(const unsigned short* __restrict__ sqHi,
                                               const float* __restrict__ qT,
                                               const unsigned long long* __restrict__ wordsg,
                                               const float* __restrict__ sning,
                                               const float* __restrict__ su2g,
                                               const unsigned long long* __restrict__ sidxpg,
                                               float* __restrict__ out) {
    __shared__ unsigned short scol[16384];       // 32 KB: [n][256] bf16 = +/- cni, XOR-swz

    const int tid = threadIdx.x;
    const int lane = tid & 63;
    const int wv = tid >> 6;                     // 0..7
    const int l15 = lane & 15;
    const int kgrp = (lane >> 4) << 3;
    const int nt = blockIdx.x, hk = blockIdx.y, b = blockIdx.z;
    const int n0 = nt * TN;
    const size_t rowbase = (size_t)(b * HK_ + hk) * N_ + n0;
    const size_t wblk = (size_t)((b * HK_ + hk) * (N_ / TN) + nt);
    const int hq = hk * G_ + (wv & 3);

    // A-fragment prefetch (latency hidden under expansion)
    const unsigned short* sqb = sqHi + (size_t)(b * HQ_ + hq) * (M_ * S_);
    short8 aq[8];
#pragma unroll
    for (int ks = 0; ks < 8; ++ks)
        aq[ks] = *reinterpret_cast<const short8*>(sqb + (size_t)l15 * S_ + ks * 32 + kgrp);

    // ---- expansion: scol[n][s] = (sign ? +1 : -1) * bf16(cni[n]); 512 threads, 2 t each ----
    {
        const int n = tid & 63;
        const int c64 = tid >> 6;                // 0..7
        const unsigned short cb = f2bf_rne(sning[rowbase + n]);
        const unsigned base = (unsigned)cb | ((unsigned)cb << 16);
        const int g = (n >> 2) & 3;
        const int r = n & 3;
        const int w = n >> 4;
        const int swz = (n & 7) << 3;
        const unsigned long long* wbp = wordsg + wblk * 256;
#pragma unroll
        for (int i = 0; i < 2; ++i) {
            const int t = c64 * 2 + i;
            const unsigned long long wd = wbp[(size_t)(w * 16 + t) * 4 + r];
            const unsigned bits = (unsigned)(wd >> (16 * g)) & 0xFFFFu;
            const unsigned nb = ~bits;
            unsigned o[8];
#pragma unroll
            for (int p = 0; p < 8; ++p) {
                const unsigned m = (((nb >> (2 * p)) & 1u) << 15) |
                                   (((nb >> (2 * p + 1)) & 1u) << 31);
                o[p] = base ^ m;
            }
            const int s0 = t * 16;
            const int e0 = n * 256 + (s0 ^ swz);
            const int e1 = n * 256 + ((s0 + 8) ^ swz);
            *reinterpret_cast<uint4_*>(&scol[e0]) = (uint4_){o[0], o[1], o[2], o[3]};
            *reinterpret_cast<uint4_*>(&scol[e1]) = (uint4_){o[4], o[5], o[6], o[7]};
        }
    }
    __syncthreads();

    // ---- GEMM + sparse part2; 2 ct per wave ----
    {
        const float* qtb = qT + (size_t)(b * HQ_ + hq) * (D_ * M_);
        const int m0 = (lane >> 4) << 2;
        const int ctb = (wv >> 2) * 2;
#pragma unroll
        for (int ci = 0; ci < 2; ++ci) {
            const int ct = ctb + ci;
            const int n = 16 * ct + l15;
            const size_t row = rowbase + n;
            const unsigned long long ip = sidxpg[row];
            const f32x4 s01 = *reinterpret_cast<const f32x4*>(su2g + row * O_);
            const f32x4 s23 = *reinterpret_cast<const f32x4*>(su2g + row * O_ + 4);
            const int nswz = (n & 7) << 3;
            f32x4 acc = (f32x4){0.f, 0.f, 0.f, 0.f};
#pragma unroll
            for (int ks = 0; ks < 8; ++ks) {
                const int ei = n * 256 + ((ks * 32 + kgrp) ^ nswz);
                const short8 bs = *reinterpret_cast<const short8*>(&scol[ei]);
                acc = __builtin_amdgcn_mfma_f32_16x16x32_bf16(aq[ks], bs, acc, 0, 0, 0);
            }
            float a0 = 0.f, a1 = 0.f, a2 = 0.f, a3 = 0.f;
#pragma unroll
            for (int j = 0; j < O_; ++j) {
                const float uj = (j < 4) ? s01[j & 3] : s23[j & 3];
                const int ix = (int)((ip >> (8 * j)) & 0x7Fu);
                const float4 qv = *reinterpret_cast<const float4*>(qtb + ix * M_ + m0);
                a0 = fmaf(uj, qv.x, a0);
                a1 = fmaf(uj, qv.y, a1);
                a2 = fmaf(uj, qv.z, a2);
                a3 = fmaf(uj, qv.w, a3);
            }
            acc[0] += a0; acc[1] += a1; acc[2] += a2; acc[3] += a3;
            float* ob = out + ((size_t)(b * HQ_ + hq) * N_ + (n0 + n)) * M_ + m0;
            *reinterpret_cast<f32x4*>(ob) = acc;
        }
    }
}

extern "C" void kernel_launch(void* const* d_in, const int* in_sizes, int n_in,
                              void* d_out, int out_size, void* d_ws, size_t ws_size,
                              hipStream_t stream) {
    const float* query = (const float*)d_in[0];  // [B][HQ][M][D]
    const float* data  = (const float*)d_in[1];  // [B][HK][N][D]
    const float* proj  = (const float*)d_in[2];  // [D][S]
    const int*   oidx  = (const int*)d_in[3];    // [B][HK][N][O]

    float* out = (float*)d_out;                  // [B][HQ][N][M]

    char* ws = (char*)d_ws;
    unsigned short* sqHi  = (unsigned short*)(ws);                     // 1 MB
    float*          qT    = (float*)(ws + (1 << 20));                  // 1 MB
    unsigned short* PtHi  = (unsigned short*)(ws + (2 << 20));         // 64 KB
    unsigned short* PtLo  = (unsigned short*)(ws + (2 << 20) + (64 << 10));   // 64 KB
    float*          Pt32  = (float*)(ws + (2 << 20) + (128 << 10));    // 128 KB
    unsigned long long* wordsg = (unsigned long long*)(ws + (3 << 20)); // 8 MB
    float*          sning = (float*)(ws + (11 << 20));                 // 1 MB
    float*          su2g  = (float*)(ws + (12 << 20));                 // 8 MB
    unsigned long long* sidxpg = (unsigned long long*)(ws + (20 << 20)); // 2 MB

    qjl_prept<<<dim3(D_), dim3(S_), 0, stream>>>(proj, PtHi, PtLo, Pt32);
    qjl_sketch_q<<<dim3(B_ * HQ_), dim3(256), 0, stream>>>(query, proj, sqHi, qT);
    qjl_signs<<<dim3(N_ / TN, HK_, B_), dim3(512), 0, stream>>>(
        data, proj, oidx, PtHi, PtLo, Pt32, wordsg, sning, su2g, sidxpg);
    qjl_out<<<dim3(N_ / TN, HK_, B_), dim3(512), 0, stream>>>(
        sqHi, qT, wordsg, sning, su2g, sidxpg, out);
}